// Round 15
// baseline (574.569 us; speedup 1.0000x reference)
//
#include <hip/hip_runtime.h>
#include <math.h>

#define Bn 16
#define Cn 64
#define NPIX 16384
#define HIDN 4

typedef unsigned short ushort_t;
typedef short bf16x8 __attribute__((ext_vector_type(8)));
typedef float f32x4 __attribute__((ext_vector_type(4)));
#define MFMA16 __builtin_amdgcn_mfma_f32_16x16x32_bf16

// workspace offsets (floats); h fp32 channel-major [b][c][pix] at 0
#define WS_H     0
#define WS_W2B   16777216           // 64*4
#define WS_G0    (WS_W2B + 256)
#define WS_XM    (WS_G0 + 32)
#define WS_WTS   (WS_XM + 16)       // 4*16*64*6
#define WS_AP    (WS_WTS + 24576)   // 16*4*64*64
#define WS_BANDS (WS_AP + 262144)
#define WS_CORR  (WS_BANDS + 262144)
#define WS_FC2S  (WS_CORR + 262144) // fc2 bf16 hi[8192] + lo[8192] shorts
#define WS_W0S   (WS_FC2S + 8192)   // (W0+I) bf16 hi[16384] + lo[16384] shorts
#define WS_QS    (WS_W0S + 16384)   // quadrant sums [b][c][16][16] = 262144 floats

__device__ __forceinline__ float mishf(float t) {
    // fast mish: __expf + fast divide (err ~1e-6 rel, far under budget)
    float e = __expf(fminf(t, 30.0f));
    float a = 1.0f + e;
    float a2 = a * a;
    return t * __fdividef(a2 - 1.0f, a2 + 1.0f);
}

// RNE hi + truncated lo split: x ~= hi + lo, err ~2^-17 rel
__device__ __forceinline__ void split_bf16(float x, ushort_t& hi, ushort_t& lo) {
    unsigned u = __float_as_uint(x);
    unsigned r = (u + 0x7FFFu + ((u >> 16) & 1u)) >> 16;
    hi = (ushort_t)r;
    float l = x - __uint_as_float(r << 16);
    lo = (ushort_t)(__float_as_uint(l) >> 16);
}

// ---- tiny prep: W2 = fc1@fc0 (+bias), g0 = label.Wg ----
__global__ void prep_kernel(const float* __restrict__ fc0_w, const float* __restrict__ fc0_b,
                            const float* __restrict__ fc1_w, const float* __restrict__ fc1_b,
                            const float* __restrict__ label, const float* __restrict__ Wg,
                            float* __restrict__ ws) {
    int t = threadIdx.x;
    if (t < 64) {
        int c = t;
        float a0 = 0.f, a1 = 0.f, a2 = 0.f, ab = 0.f;
        for (int k = 0; k < 64; ++k) {
            float f = fc1_w[c * 64 + k];
            a0 += f * fc0_w[k * 3 + 0];
            a1 += f * fc0_w[k * 3 + 1];
            a2 += f * fc0_w[k * 3 + 2];
            ab += f * fc0_b[k];
        }
        ws[WS_W2B + c * 4 + 0] = a0;
        ws[WS_W2B + c * 4 + 1] = a1;
        ws[WS_W2B + c * 4 + 2] = a2;
        ws[WS_W2B + c * 4 + 3] = ab + fc1_b[c];
    } else if (t < 96) {
        int idx = t - 64;
        int hd = idx >> 3, e = idx & 7;
        float s = 0.f;
        for (int l = 0; l < 8; ++l) s += label[l] * Wg[(hd * 8 + l) * 8 + e];
        ws[WS_G0 + idx] = s;
    }
}

// ---- pre-split weights to bf16 hi/lo (once) ----
__global__ void wsplit_kernel(const float* __restrict__ w0_w, const float* __restrict__ fc2_w,
                              float* __restrict__ ws) {
    int gid = blockIdx.x * 256 + threadIdx.x;   // 96*256 = 24576
    ushort_t* w0hi = (ushort_t*)(ws + WS_W0S);
    ushort_t* w0lo = w0hi + 16384;
    ushort_t* fc2hi = (ushort_t*)(ws + WS_FC2S);
    ushort_t* fc2lo = fc2hi + 8192;
    if (gid < 16384) {
        int o = (gid >> 6) & 63, i = gid & 63;
        float v = w0_w[gid] + ((o == i) ? 1.0f : 0.0f);   // W0 + I (residual folded)
        ushort_t h, l; split_bf16(v, h, l);
        w0hi[gid] = h; w0lo[gid] = l;
    } else if (gid < 24576) {
        int k = gid - 16384;
        ushort_t h, l; split_bf16(fc2_w[k], h, l);
        fc2hi[k] = h; fc2lo[k] = l;
    }
}

// ---- zero quadrant-sum buffer ----
__global__ void qszero_kernel(float* __restrict__ ws) {
    int gid = blockIdx.x * 256 + threadIdx.x;   // 256 blocks -> 65536 float4
    *(float4*)(ws + WS_QS + gid * 4) = make_float4(0.f, 0.f, 0.f, 0.f);
}

// ---- derive 4 coarsest bands from quadrant sums ----
__global__ void qs2bands_kernel(float* __restrict__ ws) {
    int flat = blockIdx.x * 256 + threadIdx.x;  // 65536 = 16*64*64
    int b = flat >> 12, c = (flat >> 6) & 63, cell = flat & 63;
    int X = cell >> 3, Y = cell & 7;
    const float* Q = ws + WS_QS + ((b * 64 + c) << 8);
    float q00 = Q[(2 * X) * 16 + 2 * Y],     q01 = Q[(2 * X) * 16 + 2 * Y + 1];
    float q10 = Q[(2 * X + 1) * 16 + 2 * Y], q11 = Q[(2 * X + 1) * 16 + 2 * Y + 1];
    float* bd = ws + WS_BANDS + (size_t)b * 16384 + c * 64 + cell;
    bd[0]     = (q00 + q01 + q10 + q11) * 0.0625f;
    bd[4096]  = (q00 - q01 + q10 - q11) * 0.0625f;
    bd[8192]  = (q00 + q01 - q10 - q11) * 0.0625f;
    bd[12288] = (q00 - q01 - q10 + q11) * 0.0625f;
}

// ---- xmean[b] ----
__global__ void xmean_kernel(const float* __restrict__ x, float* __restrict__ ws) {
    int b = blockIdx.x, t = threadIdx.x;
    float s = 0.f;
    for (int i = t; i < NPIX; i += 256) s += x[b * NPIX + i];
    for (int off = 32; off > 0; off >>= 1) s += __shfl_down(s, off);
    __shared__ float ps[4];
    if ((t & 63) == 0) ps[t >> 6] = s;
    __syncthreads();
    if (t == 0) ws[WS_XM + b] = (ps[0] + ps[1] + ps[2] + ps[3]) * (1.0f / NPIX);
}

// ---- gates: wts[hd][b][c][6] ----
__global__ void gates_kernel(const float* __restrict__ vg, float* __restrict__ ws) {
    int b = blockIdx.x, t = threadIdx.x;
    int c = t & 63, hd = t >> 6;
    const float* W2 = ws + WS_W2B + c * 4;
    float pooled = W2[0] * ws[WS_XM + b] + 0.5f * (W2[1] + W2[2]) + W2[3];
    float lg[8], m = -1e30f;
    for (int e = 0; e < 8; ++e) {
        lg[e] = ws[WS_G0 + hd * 8 + e] + pooled * vg[hd * 8 + e];
        m = fmaxf(m, lg[e]);
    }
    float s = 0.f;
    for (int e = 0; e < 8; ++e) { lg[e] = expf(lg[e] - m); s += lg[e]; }
    float inv = 1.0f / s;
    float* o = ws + WS_WTS + ((hd * 16 + b) * 64 + c) * 6;
    o[0] = lg[0] * inv; o[1] = lg[1] * inv; o[2] = lg[2] * inv;
    o[3] = lg[3] * inv; o[4] = (lg[4] + lg[6]) * inv; o[5] = (lg[5] + lg[7]) * inv;
}

// ---- stem: h = W2.[x,gx,gy] + b2 (fp32 channel-major) + quadrant accumulation ----
__global__ void h1_kernel(const float* __restrict__ x, float* __restrict__ ws) {
    int gid = blockIdx.x * 256 + threadIdx.x;
    int base = gid * 4;
    int b = base >> 20;
    int rem = base & 1048575;
    int c = rem >> 14;
    int pix = rem & 16383;
    int p = pix >> 7, q = pix & 127;
    const float* W2 = ws + WS_W2B + c * 4;
    float w0 = W2[0], w1 = W2[1], w2 = W2[2], bb = W2[3];
    float4 xv = *(const float4*)(x + b * NPIX + pix);
    float gx = p * (1.0f / 127.0f);
    float gy0 = q * (1.0f / 127.0f);
    const float step = 1.0f / 127.0f;
    float4 o;
    o.x = w0 * xv.x + w1 * gx + w2 * gy0 + bb;
    o.y = w0 * xv.y + w1 * gx + w2 * (gy0 + step) + bb;
    o.z = w0 * xv.z + w1 * gx + w2 * (gy0 + 2.f * step) + bb;
    o.w = w0 * xv.w + w1 * gx + w2 * (gy0 + 3.f * step) + bb;
    *(float4*)(ws + WS_H + base) = o;
    // quadrant-sum accumulation (4 px are within one 8-col group; pair lanes share it)
    float s = o.x + o.y + o.z + o.w;
    s += __shfl_xor(s, 1);
    if (!(threadIdx.x & 1))
        atomicAdd(ws + WS_QS + ((b * 64 + c) * 16 + (p >> 3)) * 16 + (q >> 3), s);
}

// ---- per-layer: effective mixing matrices A'[b][k][i][o] ----
__global__ void ap_kernel(const float* __restrict__ exp_w, float* __restrict__ ws, int hd) {
    int flat = blockIdx.x * 256 + threadIdx.x;     // 2^18
    int o = flat & 63;
    int i = (flat >> 6) & 63;
    int k = (flat >> 12) & 3;
    int b = flat >> 14;
    float acc = (i == o) ? -1.0f : 0.0f;
    const float* w = ws + WS_WTS + ((hd * 16 + b) * 64 + o) * 6;
    const float* ew = exp_w + (size_t)((hd * 8) * 4 + k) * 4096 + i * 64 + o;
    #pragma unroll
    for (int e = 0; e < 6; ++e) acc += w[e] * ew[(size_t)e * 16384];
    ws[WS_AP + flat] = acc;
}

// ---- per-layer: corr[b][k][o][xy] = sum_i A'[b][k][i][o] * bands[b][k][i][xy] ----
__global__ void mix_kernel(float* __restrict__ ws) {
    int bi = blockIdx.x;            // 64 = b*4+k
    int t = threadIdx.x;
    __shared__ float sA[64][65];
    __shared__ float sB[64][64];
    const float* Ap = ws + WS_AP + (size_t)bi * 4096;
    const float* Bd = ws + WS_BANDS + (size_t)bi * 4096;
    for (int it = 0; it < 16; ++it) {
        int flat = it * 256 + t;
        sA[flat >> 6][flat & 63] = Ap[flat];
        sB[flat >> 6][flat & 63] = Bd[flat];
    }
    __syncthreads();
    int xy = t & 63, ob = (t >> 6) * 16;
    float acc[16];
    #pragma unroll
    for (int j = 0; j < 16; ++j) acc[j] = 0.f;
    for (int i = 0; i < 64; ++i) {
        float v = sB[i][xy];
        #pragma unroll
        for (int j = 0; j < 16; ++j) acc[j] = fmaf(sA[i][ob + j], v, acc[j]);
    }
    float* out = ws + WS_CORR + (size_t)bi * 4096 + xy;
    #pragma unroll
    for (int j = 0; j < 16; ++j) out[(ob + j) * 64] = acc[j];
}

// ---- per-layer main (MFMA): h = act((W0+I)h + b0 + U(corr)) in place ----
// A-fragments from pre-split global weights; h-tile staged in LDS;
// fused quadrant-sum accumulation for the NEXT layer's bands (act layers only).
__global__ void __launch_bounds__(256) conv_mfma(
        float* __restrict__ hbuf, float* __restrict__ ws,
        const float* __restrict__ w0_b, int hd, int act) {
    int bi = blockIdx.x;            // 4096
    int b = bi >> 8, r = bi & 255;
    int row = r >> 1, qh = (r & 1) * 64;
    int t = threadIdx.x;
    __shared__ short sBhi[64][72];  // h tile, [px][i]
    __shared__ short sBlo[64][72];
    __shared__ float sCorr[8][64];  // [qg][o]

    const float* hbase = hbuf + (size_t)b * 64 * NPIX + row * 128 + qh;
    {
        int px = t & 63, lane4 = t >> 6;
        for (int rep = 0; rep < 8; ++rep) {
            int c0 = rep * 8 + lane4 * 2;
            float v0 = hbase[(size_t)c0 * NPIX + px];
            float v1 = hbase[(size_t)(c0 + 1) * NPIX + px];
            ushort_t h0, l0, h1, l1;
            split_bf16(v0, h0, l0);
            split_bf16(v1, h1, l1);
            *(unsigned*)&sBhi[px][c0] = (unsigned)h0 | ((unsigned)h1 << 16);
            *(unsigned*)&sBlo[px][c0] = (unsigned)l0 | ((unsigned)l1 << 16);
        }
    }
    {
        int X = row >> 4;
        float si = ((row >> 3) & 1) ? -1.f : 1.f;
        for (int rep = 0; rep < 2; ++rep) {
            int idx = rep * 256 + t;        // 512
            int o = idx & 63, qg = idx >> 6;
            int Y = (r & 1) * 4 + (qg >> 1);
            float sj = (qg & 1) ? -1.f : 1.f;
            const float* cb = ws + WS_CORR + (size_t)b * 16384 + o * 64 + X * 8 + Y;
            sCorr[qg][o] = w0_b[hd * 64 + o] +
                           0.0625f * (cb[0] + sj * cb[4096] + si * cb[8192] + si * sj * cb[12288]);
        }
    }
    int w = t >> 6, l = t & 63;
    int lr = l & 15, lk = l >> 4;
    const ushort_t* w0hi = (const ushort_t*)(ws + WS_W0S) + hd * 4096;
    const ushort_t* w0lo = w0hi + 16384;
    bf16x8 Ah[4][2], Al[4][2];
    #pragma unroll
    for (int m = 0; m < 4; ++m) {
        int o0 = 16 * m + lr;
        Ah[m][0] = *(const bf16x8*)(w0hi + o0 * 64 + 8 * lk);
        Ah[m][1] = *(const bf16x8*)(w0hi + o0 * 64 + 32 + 8 * lk);
        Al[m][0] = *(const bf16x8*)(w0lo + o0 * 64 + 8 * lk);
        Al[m][1] = *(const bf16x8*)(w0lo + o0 * 64 + 32 + 8 * lk);
    }
    __syncthreads();

    int px = 16 * w + lr;
    bf16x8 Bh0 = *(const bf16x8*)&sBhi[px][8 * lk];
    bf16x8 Bh1 = *(const bf16x8*)&sBhi[px][32 + 8 * lk];
    bf16x8 Bl0 = *(const bf16x8*)&sBlo[px][8 * lk];
    bf16x8 Bl1 = *(const bf16x8*)&sBlo[px][32 + 8 * lk];
    int qg = px >> 3;
    int X2 = row >> 3, Y2 = (qh + px) >> 3;
    float* qsb = ws + WS_QS + (size_t)(b * 64) * 256;
    float* outp = hbuf + (size_t)(b * 64 + 4 * lk) * NPIX + row * 128 + qh + px;
    #pragma unroll
    for (int m = 0; m < 4; ++m) {
        f32x4 a = {0.f, 0.f, 0.f, 0.f};
        a = MFMA16(Ah[m][0], Bh0, a, 0, 0, 0);
        a = MFMA16(Ah[m][1], Bh1, a, 0, 0, 0);
        a = MFMA16(Ah[m][0], Bl0, a, 0, 0, 0);
        a = MFMA16(Ah[m][1], Bl1, a, 0, 0, 0);
        a = MFMA16(Al[m][0], Bh0, a, 0, 0, 0);
        a = MFMA16(Al[m][1], Bh1, a, 0, 0, 0);
        float4 c4 = *(const float4*)&sCorr[qg][16 * m + 4 * lk];
        float cv[4] = {c4.x, c4.y, c4.z, c4.w};
        #pragma unroll
        for (int rr = 0; rr < 4; ++rr) {
            float v = a[rr] + cv[rr];
            if (act) v = mishf(v);
            outp[(size_t)(16 * m + rr) * NPIX] = v;
            if (act) {
                // 8-lane (same col-group) reduce, then one atomic per (o, group)
                float s = v;
                s += __shfl_xor(s, 1);
                s += __shfl_xor(s, 2);
                s += __shfl_xor(s, 4);
                if ((lr & 7) == 0) {
                    int o = 16 * m + 4 * lk + rr;
                    atomicAdd(qsb + (o * 16 + X2) * 16 + Y2, s);
                }
            }
        }
    }
}

// ---- final (MFMA): out = fc3 . mish(fc2 h + b2f) + b3 ----
__global__ void __launch_bounds__(256) final_mfma(
        const float* __restrict__ hbuf, const float* __restrict__ ws,
        const float* __restrict__ fc2_b, const float* __restrict__ fc3_w,
        const float* __restrict__ fc3_b, float* __restrict__ out) {
    int bi = blockIdx.x;            // 4096
    int b = bi >> 8, r = bi & 255;
    int row = r >> 1, qh = (r & 1) * 64;
    int t = threadIdx.x;
    __shared__ short sBhi[64][72];   // h tile [px][i]
    __shared__ short sBlo[64][72];
    __shared__ float sB2[128];
    __shared__ float sF3[128];

    const float* hbase = hbuf + (size_t)b * 64 * NPIX + row * 128 + qh;
    {
        int px = t & 63, lane4 = t >> 6;
        for (int rep = 0; rep < 8; ++rep) {
            int c0 = rep * 8 + lane4 * 2;
            float v0 = hbase[(size_t)c0 * NPIX + px];
            float v1 = hbase[(size_t)(c0 + 1) * NPIX + px];
            ushort_t h0, l0, h1, l1;
            split_bf16(v0, h0, l0);
            split_bf16(v1, h1, l1);
            *(unsigned*)&sBhi[px][c0] = (unsigned)h0 | ((unsigned)h1 << 16);
            *(unsigned*)&sBlo[px][c0] = (unsigned)l0 | ((unsigned)l1 << 16);
        }
        if (t < 128) { sB2[t] = fc2_b[t]; sF3[t] = fc3_w[t]; }
    }
    __syncthreads();

    int w = t >> 6, l = t & 63;
    int lr = l & 15, lk = l >> 4;
    int px = 16 * w + lr;
    const ushort_t* fc2hi = (const ushort_t*)(ws + WS_FC2S);
    const ushort_t* fc2lo = fc2hi + 8192;
    bf16x8 Bh0 = *(const bf16x8*)&sBhi[px][8 * lk];
    bf16x8 Bh1 = *(const bf16x8*)&sBhi[px][32 + 8 * lk];
    bf16x8 Bl0 = *(const bf16x8*)&sBlo[px][8 * lk];
    bf16x8 Bl1 = *(const bf16x8*)&sBlo[px][32 + 8 * lk];
    float partial = 0.f;
    #pragma unroll
    for (int m = 0; m < 8; ++m) {
        int j0 = 16 * m + lr;
        bf16x8 Ah0 = *(const bf16x8*)(fc2hi + j0 * 64 + 8 * lk);
        bf16x8 Ah1 = *(const bf16x8*)(fc2hi + j0 * 64 + 32 + 8 * lk);
        bf16x8 Al0 = *(const bf16x8*)(fc2lo + j0 * 64 + 8 * lk);
        bf16x8 Al1 = *(const bf16x8*)(fc2lo + j0 * 64 + 32 + 8 * lk);
        f32x4 a = {0.f, 0.f, 0.f, 0.f};
        a = MFMA16(Ah0, Bh0, a, 0, 0, 0);
        a = MFMA16(Ah1, Bh1, a, 0, 0, 0);
        a = MFMA16(Ah0, Bl0, a, 0, 0, 0);
        a = MFMA16(Ah1, Bl1, a, 0, 0, 0);
        a = MFMA16(Al0, Bh0, a, 0, 0, 0);
        a = MFMA16(Al1, Bh1, a, 0, 0, 0);
        float4 b4 = *(const float4*)&sB2[16 * m + 4 * lk];
        float4 f4 = *(const float4*)&sF3[16 * m + 4 * lk];
        float bv[4] = {b4.x, b4.y, b4.z, b4.w};
        float fv[4] = {f4.x, f4.y, f4.z, f4.w};
        #pragma unroll
        for (int rr = 0; rr < 4; ++rr)
            partial = fmaf(fv[rr], mishf(a[rr] + bv[rr]), partial);
    }
    partial += __shfl_xor(partial, 16, 64);
    partial += __shfl_xor(partial, 32, 64);
    if (lk == 0)
        out[(size_t)b * NPIX + row * 128 + qh + px] = partial + fc3_b[0];
}

extern "C" void kernel_launch(void* const* d_in, const int* in_sizes, int n_in,
                              void* d_out, int out_size, void* d_ws, size_t ws_size,
                              hipStream_t stream) {
    const float* x      = (const float*)d_in[0];
    const float* label  = (const float*)d_in[1];
    const float* fc0_w  = (const float*)d_in[2];
    const float* fc0_b  = (const float*)d_in[3];
    const float* fc1_w  = (const float*)d_in[4];
    const float* fc1_b  = (const float*)d_in[5];
    const float* gate_Wg = (const float*)d_in[6];
    const float* gate_vg = (const float*)d_in[7];
    const float* exp_w  = (const float*)d_in[8];
    const float* w0_w   = (const float*)d_in[9];
    const float* w0_b   = (const float*)d_in[10];
    const float* fc2_w  = (const float*)d_in[11];
    const float* fc2_b  = (const float*)d_in[12];
    const float* fc3_w  = (const float*)d_in[13];
    const float* fc3_b  = (const float*)d_in[14];
    float* out = (float*)d_out;
    float* ws = (float*)d_ws;
    float* hbuf = ws + WS_H;

    prep_kernel<<<1, 256, 0, stream>>>(fc0_w, fc0_b, fc1_w, fc1_b, label, gate_Wg, ws);
    wsplit_kernel<<<96, 256, 0, stream>>>(w0_w, fc2_w, ws);
    xmean_kernel<<<16, 256, 0, stream>>>(x, ws);
    gates_kernel<<<16, 256, 0, stream>>>(gate_vg, ws);
    qszero_kernel<<<256, 256, 0, stream>>>(ws);
    h1_kernel<<<16384, 256, 0, stream>>>(x, ws);
    for (int hd = 0; hd < HIDN; ++hd) {
        ap_kernel<<<1024, 256, 0, stream>>>(exp_w, ws, hd);
        qs2bands_kernel<<<256, 256, 0, stream>>>(ws);
        mix_kernel<<<64, 256, 0, stream>>>(ws);
        qszero_kernel<<<256, 256, 0, stream>>>(ws);
        conv_mfma<<<4096, 256, 0, stream>>>(hbuf, ws, w0_b, hd, hd != HIDN - 1);
    }
    final_mfma<<<4096, 256, 0, stream>>>(hbuf, ws, fc2_b, fc3_w, fc3_b, out);
}